// Round 1
// baseline (102.358 us; speedup 1.0000x reference)
//
#include <hip/hip_runtime.h>

#define B_ 4
#define N_ 2048
#define IND_ 128
#define H_ 4
#define D_ 64
#define HD_ 256
#define NW_ 64            /* N/32 words per adjacency row */
#define LEAKY 0.2f
#define BNEPS 1e-5f
#define LOG2E 1.44269504088896340736f

typedef float f32x4 __attribute__((ext_vector_type(4)));
typedef short s16x8 __attribute__((ext_vector_type(8)));
typedef unsigned int u32x4 __attribute__((ext_vector_type(4)));

static __device__ __forceinline__ unsigned short f2bf(float f) {
  unsigned u = __builtin_bit_cast(unsigned, f);
  u = (u + 0x7fffu + ((u >> 16) & 1u)) >> 16;   // RNE
  return (unsigned short)u;
}
static __device__ __forceinline__ float bf2f(unsigned short s) {
  unsigned u = ((unsigned)s) << 16;
  return __builtin_bit_cast(float, u);
}

// ---------------- Kernel A: pack adjacency into bitmask -------------------
__global__ __launch_bounds__(256) void k_pack_adj(const int* __restrict__ adj,
                                                  unsigned* __restrict__ bits) {
  int idx = blockIdx.x * 256 + threadIdx.x;     // flat over N*N (row-major)
  int val = adj[idx] != 0;
  unsigned long long m = __ballot(val);
  int lane = threadIdx.x & 63;
  if (lane == 0)       bits[idx >> 5] = (unsigned)m;
  else if (lane == 32) bits[idx >> 5] = (unsigned)(m >> 32);
}

// ---------------- Kernel B: Wh = h @ W, store transposed bf16 -------------
// wht layout: [bh=b*H+h][d][n]  (bf16), so PV B-fragments read contiguously.
__global__ __launch_bounds__(256) void k_gemm(const float* __restrict__ h,
                                              const float* __restrict__ W,
                                              unsigned short* __restrict__ wht) {
  __shared__ float hl[32 * 128];
  __shared__ float tr[256 * 33];
  int t = threadIdx.x;
  int rowbase = blockIdx.x * 32;               // global row m in [0, B*N)
  const f32x4* hg = (const f32x4*)(h + rowbase * 128);
  f32x4* hl4 = (f32x4*)hl;
#pragma unroll
  for (int i = 0; i < 4; i++) hl4[t + i * 256] = hg[t + i * 256];
  __syncthreads();

  int lane = t & 63, q = t >> 6;
  float acc[8][4];
#pragma unroll
  for (int rr = 0; rr < 8; rr++)
#pragma unroll
    for (int cc = 0; cc < 4; cc++) acc[rr][cc] = 0.f;

  for (int k = 0; k < 128; k++) {
    f32x4 wv = *(const f32x4*)(W + k * 256 + lane * 4);
#pragma unroll
    for (int rr = 0; rr < 8; rr++) {
      float hv = hl[(q * 8 + rr) * 128 + k];
#pragma unroll
      for (int cc = 0; cc < 4; cc++) acc[rr][cc] = fmaf(hv, wv[cc], acc[rr][cc]);
    }
  }
  // transpose through LDS (pad 33 -> conflict-free)
#pragma unroll
  for (int rr = 0; rr < 8; rr++)
#pragma unroll
    for (int cc = 0; cc < 4; cc++)
      tr[(lane * 4 + cc) * 33 + q * 8 + rr] = acc[rr][cc];
  __syncthreads();

  int c = t;                 // output channel 0..255
  int d = c & 63, hh = c >> 6;
  int b = rowbase >> 11, n0 = rowbase & 2047;
  u32x4 wv[4];
#pragma unroll
  for (int i = 0; i < 4; i++) {
#pragma unroll
    for (int jj = 0; jj < 4; jj++) {
      unsigned lo = f2bf(tr[c * 33 + (i * 4 + jj) * 2]);
      unsigned hi = f2bf(tr[c * 33 + (i * 4 + jj) * 2 + 1]);
      wv[i][jj] = lo | (hi << 16);
    }
  }
  u32x4* outp = (u32x4*)(wht + ((size_t)((b * H_ + hh) * 64 + d)) * 2048 + n0);
#pragma unroll
  for (int i = 0; i < 4; i++) outp[i] = wv[i];
}

// ---------------- Kernel B2: src/dst scalars + per-(b,h) dst max ----------
__global__ __launch_bounds__(256) void k_srcdst(const unsigned short* __restrict__ wht,
                                                const float* __restrict__ a,
                                                float* __restrict__ src,
                                                float* __restrict__ dst,
                                                float* __restrict__ dmax) {
  int bh = blockIdx.x;
  int hh = bh & 3;
  int t = threadIdx.x;
  float s[8], dd[8];
#pragma unroll
  for (int k = 0; k < 8; k++) { s[k] = 0.f; dd[k] = 0.f; }
  for (int d = 0; d < 64; d++) {
    float aS = a[hh * 128 + d];
    float aD = a[hh * 128 + 64 + d];
    const unsigned short* row = wht + (size_t)(bh * 64 + d) * 2048;
#pragma unroll
    for (int k = 0; k < 8; k++) {
      float w = bf2f(row[t + 256 * k]);
      s[k] = fmaf(w, aS, s[k]);
      dd[k] = fmaf(w, aD, dd[k]);
    }
  }
  float mx = -1e30f;
#pragma unroll
  for (int k = 0; k < 8; k++) {
    src[bh * 2048 + t + 256 * k] = s[k];
    dst[bh * 2048 + t + 256 * k] = dd[k];
    mx = fmaxf(mx, dd[k]);
  }
  for (int off = 1; off < 64; off <<= 1) mx = fmaxf(mx, __shfl_xor(mx, off));
  __shared__ float red[4];
  if ((t & 63) == 0) red[t >> 6] = mx;
  __syncthreads();
  if (t == 0) dmax[bh] = fmaxf(fmaxf(red[0], red[1]), fmaxf(red[2], red[3]));
}

// ---------------- Kernel C: flash attention (masked, additive scores) -----
__global__ __launch_bounds__(256) void k_attn(const unsigned* __restrict__ adjb,
                                              const unsigned short* __restrict__ wht,
                                              const float* __restrict__ src,
                                              const float* __restrict__ dst,
                                              const float* __restrict__ dmax,
                                              float* __restrict__ hnew,
                                              float* __restrict__ chsum,
                                              float* __restrict__ chsq) {
  __shared__ unsigned adj_lds[64 * 65];   // padded: bank-conflict-free per-row reads
  __shared__ u32x4 whb4[512];             // 8KB: Wh^T tile [d=64][j=64] bf16, XOR-swizzled
  __shared__ f32x4 dst4[16];              // dst_j tile
  __shared__ float redS[4 * 64], redQ[4 * 64];

  int t = threadIdx.x;
  int bid = blockIdx.x;
  int bh = bid & 15, it = bid >> 4;       // 16 consecutive blocks share adj rows (L2)
  int b = bh >> 2, hh = bh & 3;
  int i0 = it * 64;
  int w = t >> 6, lane = t & 63, m = lane & 15, g = lane >> 4;

  for (int idx = t; idx < 64 * 64; idx += 256) {
    int r = idx >> 6, wd = idx & 63;
    adj_lds[r * 65 + wd] = adjb[(size_t)(i0 + r) * 64 + wd];
  }

  int row_i = i0 + w * 16 + m;            // A-operand row this lane fills
  float srcv = src[bh * 2048 + row_i];
  float sM = srcv + dmax[bh];
  float Mi = fmaxf(sM, LEAKY * sM);       // upper bound of row's scores
  float negMC = -Mi * LOG2E;

  f32x4 acc[4];
#pragma unroll
  for (int db = 0; db < 4; db++) acc[db] = (f32x4){0.f, 0.f, 0.f, 0.f};
  float den = 0.f;

  char* wbuf = (char*)whb4;
  float* dstl = (float*)dst4;

  for (int jt = 0; jt < 32; jt++) {
    __syncthreads();
    {   // stage Wh^T tile: 64 d-rows x 128B, swizzled at 16B granularity
      int r = t >> 2, ch = t & 3;
      const u32x4* gp = (const u32x4*)(wht + (size_t)(bh * 64 + r) * 2048 + jt * 64 + ch * 16);
      u32x4 v0 = gp[0], v1 = gp[1];
      int sw = (r & 7) << 4;
      *(u32x4*)(wbuf + r * 128 + ((ch * 32) ^ sw)) = v0;
      *(u32x4*)(wbuf + r * 128 + ((ch * 32 + 16) ^ sw)) = v1;
      if (t < 64) dstl[t] = dst[bh * 2048 + jt * 64 + t];
    }
    __syncthreads();

#pragma unroll
    for (int ks = 0; ks < 2; ks++) {
      unsigned adjw = adj_lds[(w * 16 + m) * 65 + jt * 2 + ks];
      unsigned bits = (adjw >> (g * 8)) & 0xffu;
      f32x4 dv0 = *(f32x4*)&dstl[ks * 32 + g * 8];
      f32x4 dv1 = *(f32x4*)&dstl[ks * 32 + g * 8 + 4];
      s16x8 af;
#pragma unroll
      for (int e = 0; e < 8; e++) {
        float dj = (e < 4) ? dv0[e] : dv1[e - 4];
        float sv = srcv + dj;
        float el = fmaxf(sv, LEAKY * sv);                 // LeakyReLU
        float p = exp2f(fmaf(el, LOG2E, negMC));          // exp(e - Mi)
        p = ((bits >> e) & 1u) ? p : 0.f;                 // mask
        den += p;
        af[e] = (short)f2bf(p);
      }
#pragma unroll
      for (int db = 0; db < 4; db++) {
        int dl = db * 16 + m;
        int off = dl * 128 + ((ks * 64 + g * 16) ^ ((dl & 7) << 4));
        s16x8 bf = *(const s16x8*)(wbuf + off);
        acc[db] = __builtin_amdgcn_mfma_f32_16x16x32_bf16(af, bf, acc[db], 0, 0, 0);
      }
    }
  }

  // full denominator for row m (sum across the 4 k-groups)
  den += __shfl_xor(den, 16);
  den += __shfl_xor(den, 32);

  float sums[4] = {0.f, 0.f, 0.f, 0.f}, sqs[4] = {0.f, 0.f, 0.f, 0.f};
#pragma unroll
  for (int r = 0; r < 4; r++) {
    float dr = __shfl(den, 4 * g + r);      // denominator for D-layout row 4g+r
    float inv = dr > 0.f ? 1.0f / dr : 0.f; // all-masked row -> zeros (nan_to_num)
    int n = i0 + w * 16 + 4 * g + r;
#pragma unroll
    for (int db = 0; db < 4; db++) {
      float val = acc[db][r] * inv;
      hnew[(size_t)(b * 2048 + n) * 256 + hh * 64 + db * 16 + m] = val;
      sums[db] += val;
      sqs[db] += val * val;
    }
  }
#pragma unroll
  for (int db = 0; db < 4; db++) {
    sums[db] += __shfl_xor(sums[db], 16); sums[db] += __shfl_xor(sums[db], 32);
    sqs[db]  += __shfl_xor(sqs[db], 16);  sqs[db]  += __shfl_xor(sqs[db], 32);
  }
  if (g == 0) {
#pragma unroll
    for (int db = 0; db < 4; db++) {
      redS[w * 64 + db * 16 + m] = sums[db];
      redQ[w * 64 + db * 16 + m] = sqs[db];
    }
  }
  __syncthreads();
  if (t < 64) {
    float ts = redS[t] + redS[64 + t] + redS[128 + t] + redS[192 + t];
    float tq = redQ[t] + redQ[64 + t] + redQ[128 + t] + redQ[192 + t];
    atomicAdd(&chsum[hh * 64 + t], ts);
    atomicAdd(&chsq[hh * 64 + t], tq);
  }
}

// ---------------- Kernel D: BN stats -> scale/shift -----------------------
__global__ void k_stats(const float* __restrict__ chsum, const float* __restrict__ chsq,
                        const float* __restrict__ gamma, const float* __restrict__ beta,
                        float* __restrict__ scale, float* __restrict__ shift) {
  int c = threadIdx.x;
  float mean = chsum[c] * (1.0f / 8192.0f);
  float var = chsq[c] * (1.0f / 8192.0f) - mean * mean;
  float sc = gamma[c] * rsqrtf(var + BNEPS);
  scale[c] = sc;
  shift[c] = beta[c] - mean * sc;
}

// ---------------- Kernel E: BN apply + ELU --------------------------------
__global__ __launch_bounds__(256) void k_bn_elu(const float* __restrict__ hnew,
                                                const float* __restrict__ scale,
                                                const float* __restrict__ shift,
                                                float* __restrict__ out) {
  int idx4 = blockIdx.x * 256 + threadIdx.x;
  f32x4 x = ((const f32x4*)hnew)[idx4];
  int c0 = (idx4 * 4) & 255;
  f32x4 sc = *(const f32x4*)(scale + c0);
  f32x4 sh = *(const f32x4*)(shift + c0);
  f32x4 y;
#pragma unroll
  for (int e = 0; e < 4; e++) {
    float v = fmaf(x[e], sc[e], sh[e]);
    y[e] = v > 0.f ? v : expm1f(v);
  }
  ((f32x4*)out)[idx4] = y;
}

extern "C" void kernel_launch(void* const* d_in, const int* in_sizes, int n_in,
                              void* d_out, int out_size, void* d_ws, size_t ws_size,
                              hipStream_t stream) {
  const float* h = (const float*)d_in[0];
  const float* W = (const float*)d_in[1];
  const float* a = (const float*)d_in[2];
  const float* gamma = (const float*)d_in[3];
  const float* beta = (const float*)d_in[4];
  const int* adj = (const int*)d_in[5];

  char* ws = (char*)d_ws;
  unsigned* adjb = (unsigned*)ws;                                  // 512 KB
  unsigned short* wht = (unsigned short*)(ws + (512 << 10));       // 4 MB
  float* src = (float*)(ws + (512 << 10) + (4 << 20));             // 128 KB
  float* dst = src + 16 * 2048;                                    // 128 KB
  float* dmax = dst + 16 * 2048;                                   // 16
  float* chsum = dmax + 64;                                        // 256
  float* chsq = chsum + 256;                                       // 256
  float* scale = chsq + 256;                                       // 256
  float* shift = scale + 256;                                      // 256
  float* hnew = (float*)(ws + (512 << 10) + (5 << 20));            // 8 MB

  hipMemsetAsync(chsum, 0, 512 * sizeof(float), stream);

  k_pack_adj<<<(N_ * N_) / 256, 256, 0, stream>>>(adj, adjb);
  k_gemm<<<(B_ * N_) / 32, 256, 0, stream>>>(h, W, wht);
  k_srcdst<<<B_ * H_, 256, 0, stream>>>(wht, a, src, dst, dmax);
  k_attn<<<B_ * H_ * (N_ / 64), 256, 0, stream>>>(adjb, wht, src, dst, dmax,
                                                  hnew, chsum, chsq);
  k_stats<<<1, 256, 0, stream>>>(chsum, chsq, gamma, beta, scale, shift);
  k_bn_elu<<<(B_ * N_ * HD_) / 1024, 256, 0, stream>>>(hnew, scale, shift,
                                                       (float*)d_out);
}

// Round 2
// 84.959 us; speedup vs baseline: 1.2048x; 1.2048x over previous
//
#include <hip/hip_runtime.h>

#define B_ 4
#define N_ 2048
#define IND_ 128
#define H_ 4
#define D_ 64
#define HD_ 256
#define LEAKY 0.2f
#define BNEPS 1e-5f
#define LOG2E 1.44269504088896340736f

typedef float f32x4 __attribute__((ext_vector_type(4)));
typedef short s16x8 __attribute__((ext_vector_type(8)));
typedef unsigned int u32x4 __attribute__((ext_vector_type(4)));

static __device__ __forceinline__ unsigned short f2bf(float f) {
  unsigned u = __builtin_bit_cast(unsigned, f);
  u = (u + 0x7fffu + ((u >> 16) & 1u)) >> 16;   // RNE
  return (unsigned short)u;
}
static __device__ __forceinline__ unsigned encf(float f) {
  unsigned u = __builtin_bit_cast(unsigned, f);
  return (u & 0x80000000u) ? ~u : (u | 0x80000000u);
}
static __device__ __forceinline__ float decf(unsigned u) {
  unsigned b = (u & 0x80000000u) ? (u ^ 0x80000000u) : ~u;
  return __builtin_bit_cast(float, b);
}

// ---------------- Kernel A: pack adjacency into bitmask -------------------
__global__ __launch_bounds__(256) void k_pack_adj(const int* __restrict__ adj,
                                                  unsigned* __restrict__ bits) {
  int idx = blockIdx.x * 256 + threadIdx.x;     // flat over N*N (row-major)
  int val = adj[idx] != 0;
  unsigned long long m = __ballot(val);
  int lane = threadIdx.x & 63;
  if (lane == 0)       bits[idx >> 5] = (unsigned)m;
  else if (lane == 32) bits[idx >> 5] = (unsigned)(m >> 32);
}

// ---------------- Kernel B: Wh = h @ W (bf16, transposed) + src/dst -------
// wht layout: [bh=b*H+h][d][n]  (bf16). Also emits srcL/dstL (pre-scaled by
// log2e) and per-bh dstL max via order-preserving-uint atomicMax.
__global__ __launch_bounds__(256) void k_gemm(const float* __restrict__ h,
                                              const float* __restrict__ W,
                                              const float* __restrict__ a,
                                              unsigned short* __restrict__ wht,
                                              float* __restrict__ src,
                                              float* __restrict__ dst,
                                              unsigned* __restrict__ dmaxU) {
  __shared__ float hl[32 * 128];
  __shared__ float tr[256 * 33];
  int t = threadIdx.x;
  int rowbase = blockIdx.x * 32;               // global row m in [0, B*N)
  const f32x4* hg = (const f32x4*)(h + rowbase * 128);
  f32x4* hl4 = (f32x4*)hl;
#pragma unroll
  for (int i = 0; i < 4; i++) hl4[t + i * 256] = hg[t + i * 256];
  __syncthreads();

  int lane = t & 63, q = t >> 6;
  float acc[8][4];
#pragma unroll
  for (int rr = 0; rr < 8; rr++)
#pragma unroll
    for (int cc = 0; cc < 4; cc++) acc[rr][cc] = 0.f;

  for (int k = 0; k < 128; k++) {
    f32x4 wv = *(const f32x4*)(W + k * 256 + lane * 4);
#pragma unroll
    for (int rr = 0; rr < 8; rr++) {
      float hv = hl[(q * 8 + rr) * 128 + k];
#pragma unroll
      for (int cc = 0; cc < 4; cc++) acc[rr][cc] = fmaf(hv, wv[cc], acc[rr][cc]);
    }
  }

  // ---- fused src/dst: channels owned by this thread all share hh=lane>>4
  int b = rowbase >> 11, n0 = rowbase & 2047;
  {
    int hh = lane >> 4;
    int dbase = (lane & 15) * 4;
    float aS[4], aD[4];
#pragma unroll
    for (int cc = 0; cc < 4; cc++) {
      aS[cc] = a[hh * 128 + dbase + cc] * LOG2E;
      aD[cc] = a[hh * 128 + 64 + dbase + cc] * LOG2E;
    }
    float dmx = -1e30f;
#pragma unroll
    for (int rr = 0; rr < 8; rr++) {
      float sv = 0.f, dv = 0.f;
#pragma unroll
      for (int cc = 0; cc < 4; cc++) {
        sv = fmaf(acc[rr][cc], aS[cc], sv);
        dv = fmaf(acc[rr][cc], aD[cc], dv);
      }
#pragma unroll
      for (int off = 1; off < 16; off <<= 1) {
        sv += __shfl_xor(sv, off);
        dv += __shfl_xor(dv, off);
      }
      if ((lane & 15) == 0) {
        int n = n0 + q * 8 + rr;
        src[(size_t)(b * 4 + hh) * 2048 + n] = sv;
        dst[(size_t)(b * 4 + hh) * 2048 + n] = dv;
        dmx = fmaxf(dmx, dv);
      }
    }
    if ((lane & 15) == 0) atomicMax(&dmaxU[b * 4 + hh], encf(dmx));
  }

  // ---- transpose through LDS (pad 33 -> conflict-free), emit bf16 wht
#pragma unroll
  for (int rr = 0; rr < 8; rr++)
#pragma unroll
    for (int cc = 0; cc < 4; cc++)
      tr[(lane * 4 + cc) * 33 + q * 8 + rr] = acc[rr][cc];
  __syncthreads();

  int c = t;                 // output channel 0..255
  int d = c & 63, hh = c >> 6;
  u32x4 wv[4];
#pragma unroll
  for (int i = 0; i < 4; i++) {
#pragma unroll
    for (int jj = 0; jj < 4; jj++) {
      unsigned lo = f2bf(tr[c * 33 + (i * 4 + jj) * 2]);
      unsigned hi = f2bf(tr[c * 33 + (i * 4 + jj) * 2 + 1]);
      wv[i][jj] = lo | (hi << 16);
    }
  }
  u32x4* outp = (u32x4*)(wht + ((size_t)((b * H_ + hh) * 64 + d)) * 2048 + n0);
#pragma unroll
  for (int i = 0; i < 4; i++) outp[i] = wv[i];
}

// ---------------- Kernel C: flash attention (masked, additive scores) -----
__global__ __launch_bounds__(256) void k_attn(const unsigned* __restrict__ adjb,
                                              const unsigned short* __restrict__ wht,
                                              const float* __restrict__ src,
                                              const float* __restrict__ dst,
                                              const unsigned* __restrict__ dmaxU,
                                              float* __restrict__ hnew,
                                              float* __restrict__ chsum,
                                              float* __restrict__ chsq) {
  __shared__ unsigned adj_lds[64 * 65];   // padded: conflict-free per-row reads
  __shared__ u32x4 whb4[1024];            // 2 x 8KB: Wh^T tile dbuf, XOR-swizzled
  __shared__ f32x4 dstl4[512];            // full dstL row for this bh (8KB)
  __shared__ float redS[4 * 64], redQ[4 * 64];

  int t = threadIdx.x;
  int bid = blockIdx.x;
  int bh = bid & 15, it = bid >> 4;       // 16 consecutive blocks share adj rows (L2)
  int b = bh >> 2, hh = bh & 3;
  int i0 = it * 64;
  int w = t >> 6, lane = t & 63, m = lane & 15, g = lane >> 4;

  for (int idx = t; idx < 64 * 64; idx += 256) {
    int r = idx >> 6, wd = idx & 63;
    adj_lds[r * 65 + wd] = adjb[(size_t)(i0 + r) * 64 + wd];
  }
  // full dstL row (log2-domain) cached in LDS once
  {
    const f32x4* dg = (const f32x4*)(dst + (size_t)bh * 2048);
    dstl4[t] = dg[t];
    dstl4[t + 256] = dg[t + 256];
  }
  const float* dstl = (const float*)dstl4;

  int row_i = i0 + w * 16 + m;            // A-operand row this lane fills
  float srcL = src[(size_t)bh * 2048 + row_i];
  float dmaxL = decf(dmaxU[bh]);
  float sML = srcL + dmaxL;
  float MiL = fmaxf(sML, LEAKY * sML);    // upper bound (log2 domain)
  float negM = -MiL;

  f32x4 acc[4];
#pragma unroll
  for (int db = 0; db < 4; db++) acc[db] = (f32x4){0.f, 0.f, 0.f, 0.f};
  float den = 0.f;

  char* wbase = (char*)whb4;
  int r_ = t >> 2, ch_ = t & 3;
  const char* gbase = (const char*)(wht + (size_t)(bh * 64 + r_) * 2048);
  int sw = (r_ & 7) << 4;
  u32x4 R0, R1;

#define LOADT(jt_) { const u32x4* gp = (const u32x4*)(gbase + (size_t)(jt_) * 128 + ch_ * 32); \
                     R0 = gp[0]; R1 = gp[1]; }
#define WRITET(pb_) { char* wb_ = (pb_); \
                      *(u32x4*)(wb_ + r_ * 128 + ((ch_ * 32) ^ sw)) = R0; \
                      *(u32x4*)(wb_ + r_ * 128 + ((ch_ * 32 + 16) ^ sw)) = R1; }

  LOADT(0); WRITET(wbase); LOADT(1);

  for (int jt = 0; jt < 32; jt++) {
    int cur = jt & 1;
    __syncthreads();                      // drains prefetch vmem + dbuf writes
    if (jt < 31) WRITET(wbase + (cur ^ 1) * 8192);   // tile jt+1 -> other buf
    if (jt < 30) LOADT(jt + 2);                      // issue tile jt+2 loads
    const char* wbufc = wbase + cur * 8192;

#pragma unroll
    for (int ks = 0; ks < 2; ks++) {
      unsigned adjw = adj_lds[(w * 16 + m) * 65 + jt * 2 + ks];
      unsigned bits = (adjw >> (g * 8)) & 0xffu;
      const float* dp = &dstl[jt * 64 + ks * 32 + g * 8];
      f32x4 dv0 = *(const f32x4*)dp;
      f32x4 dv1 = *(const f32x4*)(dp + 4);
      float pm[8];
#pragma unroll
      for (int e = 0; e < 8; e++) {
        float dj = (e < 4) ? dv0[e] : dv1[e - 4];
        float svL = srcL + dj;
        float ex = fmaxf(svL, LEAKY * svL) + negM;   // leaky in log2 domain
        float p = __builtin_amdgcn_exp2f(ex);
        unsigned keep = (unsigned)(((int)(bits << (31 - e))) >> 31);
        p = __builtin_bit_cast(float, __builtin_bit_cast(unsigned, p) & keep);
        den += p;
        pm[e] = p;
      }
      u32x4 afu;
#pragma unroll
      for (int e2 = 0; e2 < 4; e2++) {
        unsigned rr_;
        asm("v_cvt_pk_bf16_f32 %0, %1, %2" : "=v"(rr_) : "v"(pm[2 * e2]), "v"(pm[2 * e2 + 1]));
        afu[e2] = rr_;
      }
      s16x8 af = __builtin_bit_cast(s16x8, afu);
#pragma unroll
      for (int db = 0; db < 4; db++) {
        int dl = db * 16 + m;
        int off = dl * 128 + ((ks * 64 + g * 16) ^ ((dl & 7) << 4));
        s16x8 bf = *(const s16x8*)(wbufc + off);
        acc[db] = __builtin_amdgcn_mfma_f32_16x16x32_bf16(af, bf, acc[db], 0, 0, 0);
      }
    }
  }
#undef LOADT
#undef WRITET

  // full denominator for row m (sum across the 4 k-groups)
  den += __shfl_xor(den, 16);
  den += __shfl_xor(den, 32);

  float sums[4] = {0.f, 0.f, 0.f, 0.f}, sqs[4] = {0.f, 0.f, 0.f, 0.f};
#pragma unroll
  for (int r = 0; r < 4; r++) {
    float dr = __shfl(den, 4 * g + r);      // denominator for D-layout row 4g+r
    float inv = dr > 0.f ? 1.0f / dr : 0.f; // all-masked row -> zeros (nan_to_num)
    int n = i0 + w * 16 + 4 * g + r;
#pragma unroll
    for (int db = 0; db < 4; db++) {
      float val = acc[db][r] * inv;
      hnew[(size_t)(b * 2048 + n) * 256 + hh * 64 + db * 16 + m] = val;
      sums[db] += val;
      sqs[db] += val * val;
    }
  }
#pragma unroll
  for (int db = 0; db < 4; db++) {
    sums[db] += __shfl_xor(sums[db], 16); sums[db] += __shfl_xor(sums[db], 32);
    sqs[db]  += __shfl_xor(sqs[db], 16);  sqs[db]  += __shfl_xor(sqs[db], 32);
  }
  if (g == 0) {
#pragma unroll
    for (int db = 0; db < 4; db++) {
      redS[w * 64 + db * 16 + m] = sums[db];
      redQ[w * 64 + db * 16 + m] = sqs[db];
    }
  }
  __syncthreads();
  if (t < 64) {
    float ts = redS[t] + redS[64 + t] + redS[128 + t] + redS[192 + t];
    float tq = redQ[t] + redQ[64 + t] + redQ[128 + t] + redQ[192 + t];
    atomicAdd(&chsum[hh * 64 + t], ts);
    atomicAdd(&chsq[hh * 64 + t], tq);
  }
}

// ---------------- Kernel D: BN stats -> scale/shift -----------------------
__global__ void k_stats(const float* __restrict__ chsum, const float* __restrict__ chsq,
                        const float* __restrict__ gamma, const float* __restrict__ beta,
                        float* __restrict__ scale, float* __restrict__ shift) {
  int c = threadIdx.x;
  float mean = chsum[c] * (1.0f / 8192.0f);
  float var = chsq[c] * (1.0f / 8192.0f) - mean * mean;
  float sc = gamma[c] * rsqrtf(var + BNEPS);
  scale[c] = sc;
  shift[c] = beta[c] - mean * sc;
}

// ---------------- Kernel E: BN apply + ELU --------------------------------
__global__ __launch_bounds__(256) void k_bn_elu(const float* __restrict__ hnew,
                                                const float* __restrict__ scale,
                                                const float* __restrict__ shift,
                                                float* __restrict__ out) {
  int idx4 = blockIdx.x * 256 + threadIdx.x;
  f32x4 x = ((const f32x4*)hnew)[idx4];
  int c0 = (idx4 * 4) & 255;
  f32x4 sc = *(const f32x4*)(scale + c0);
  f32x4 sh = *(const f32x4*)(shift + c0);
  f32x4 y;
#pragma unroll
  for (int e = 0; e < 4; e++) {
    float v = fmaf(x[e], sc[e], sh[e]);
    y[e] = v > 0.f ? v : expm1f(v);
  }
  ((f32x4*)out)[idx4] = y;
}

extern "C" void kernel_launch(void* const* d_in, const int* in_sizes, int n_in,
                              void* d_out, int out_size, void* d_ws, size_t ws_size,
                              hipStream_t stream) {
  const float* h = (const float*)d_in[0];
  const float* W = (const float*)d_in[1];
  const float* a = (const float*)d_in[2];
  const float* gamma = (const float*)d_in[3];
  const float* beta = (const float*)d_in[4];
  const int* adj = (const int*)d_in[5];

  char* ws = (char*)d_ws;
  unsigned* adjb = (unsigned*)ws;                                  // 512 KB
  unsigned short* wht = (unsigned short*)(ws + (512 << 10));       // 4 MB
  float* src = (float*)(ws + (512 << 10) + (4 << 20));             // 128 KB
  float* dst = src + 16 * 2048;                                    // 128 KB
  float* chsum = dst + 16 * 2048;                                  // 256
  float* chsq = chsum + 256;                                       // 256
  unsigned* dmaxU = (unsigned*)(chsq + 256);                       // 16
  float* scale = (float*)(dmaxU + 64);                             // 256
  float* shift = scale + 256;                                      // 256
  float* hnew = (float*)(ws + (512 << 10) + (5 << 20));            // 8 MB

  hipMemsetAsync(chsum, 0, (256 + 256 + 64) * sizeof(float), stream);

  k_pack_adj<<<(N_ * N_) / 256, 256, 0, stream>>>(adj, adjb);
  k_gemm<<<(B_ * N_) / 32, 256, 0, stream>>>(h, W, a, wht, src, dst, dmaxU);
  k_attn<<<B_ * H_ * (N_ / 64), 256, 0, stream>>>(adjb, wht, src, dst, dmaxU,
                                                  hnew, chsum, chsq);
  k_stats<<<1, 256, 0, stream>>>(chsum, chsq, gamma, beta, scale, shift);
  k_bn_elu<<<(B_ * N_ * HD_) / 1024, 256, 0, stream>>>(hnew, scale, shift,
                                                       (float*)d_out);
}

// Round 4
// 75.971 us; speedup vs baseline: 1.3473x; 1.1183x over previous
//
#include <hip/hip_runtime.h>

#define B_ 4
#define N_ 2048
#define IND_ 128
#define H_ 4
#define D_ 64
#define HD_ 256
#define LEAKY 0.2f
#define BNEPS 1e-5f
#define LOG2E 1.44269504088896340736f

typedef float f32x4 __attribute__((ext_vector_type(4)));
typedef short s16x8 __attribute__((ext_vector_type(8)));
typedef unsigned int u32x4 __attribute__((ext_vector_type(4)));

static __device__ __forceinline__ unsigned short f2bf(float f) {
  unsigned u = __builtin_bit_cast(unsigned, f);
  u = (u + 0x7fffu + ((u >> 16) & 1u)) >> 16;   // RNE
  return (unsigned short)u;
}
static __device__ __forceinline__ unsigned encf(float f) {
  unsigned u = __builtin_bit_cast(unsigned, f);
  return (u & 0x80000000u) ? ~u : (u | 0x80000000u);
}
static __device__ __forceinline__ float decf(unsigned u) {
  unsigned b = (u & 0x80000000u) ? (u ^ 0x80000000u) : ~u;
  return __builtin_bit_cast(float, b);
}

// ---------------- Kernel A: pack adjacency + zero accumulators ------------
__global__ __launch_bounds__(256) void k_pack_adj(const int* __restrict__ adj,
                                                  unsigned* __restrict__ bits,
                                                  float* __restrict__ zbuf) {
  // zero chsum(256) | chsq(256) | dmaxU(64) = 576 floats with 256 threads
  if (blockIdx.x == 0) {
    for (int i = threadIdx.x; i < 576; i += 256) zbuf[i] = 0.f;
  }
  int idx = blockIdx.x * 256 + threadIdx.x;     // flat over N*N (row-major)
  int val = adj[idx] != 0;
  unsigned long long m = __ballot(val);
  int lane = threadIdx.x & 63;
  if (lane == 0)       bits[idx >> 5] = (unsigned)m;
  else if (lane == 32) bits[idx >> 5] = (unsigned)(m >> 32);
}

// ---------------- Kernel B: Wh = h @ W (bf16, transposed) + src/dst -------
// wht layout: [bh=b*H+h][d][n]  (bf16). Also emits srcL/dstL (pre-scaled by
// log2e) and per-bh dstL max via order-preserving-uint atomicMax.
__global__ __launch_bounds__(256) void k_gemm(const float* __restrict__ h,
                                              const float* __restrict__ W,
                                              const float* __restrict__ a,
                                              unsigned short* __restrict__ wht,
                                              float* __restrict__ src,
                                              float* __restrict__ dst,
                                              unsigned* __restrict__ dmaxU) {
  __shared__ float hl[32 * 128];
  __shared__ float tr[256 * 33];
  int t = threadIdx.x;
  int rowbase = blockIdx.x * 32;               // global row m in [0, B*N)
  const f32x4* hg = (const f32x4*)(h + rowbase * 128);
  f32x4* hl4 = (f32x4*)hl;
#pragma unroll
  for (int i = 0; i < 4; i++) hl4[t + i * 256] = hg[t + i * 256];
  __syncthreads();

  int lane = t & 63, q = t >> 6;
  float acc[8][4];
#pragma unroll
  for (int rr = 0; rr < 8; rr++)
#pragma unroll
    for (int cc = 0; cc < 4; cc++) acc[rr][cc] = 0.f;

  for (int k = 0; k < 128; k++) {
    f32x4 wv = *(const f32x4*)(W + k * 256 + lane * 4);
#pragma unroll
    for (int rr = 0; rr < 8; rr++) {
      float hv = hl[(q * 8 + rr) * 128 + k];
#pragma unroll
      for (int cc = 0; cc < 4; cc++) acc[rr][cc] = fmaf(hv, wv[cc], acc[rr][cc]);
    }
  }

  // ---- fused src/dst: channels owned by this thread all share hh=lane>>4
  int b = rowbase >> 11, n0 = rowbase & 2047;
  {
    int hh = lane >> 4;
    int dbase = (lane & 15) * 4;
    float aS[4], aD[4];
#pragma unroll
    for (int cc = 0; cc < 4; cc++) {
      aS[cc] = a[hh * 128 + dbase + cc] * LOG2E;
      aD[cc] = a[hh * 128 + 64 + dbase + cc] * LOG2E;
    }
    float dmx = -1e30f;
#pragma unroll
    for (int rr = 0; rr < 8; rr++) {
      float sv = 0.f, dv = 0.f;
#pragma unroll
      for (int cc = 0; cc < 4; cc++) {
        sv = fmaf(acc[rr][cc], aS[cc], sv);
        dv = fmaf(acc[rr][cc], aD[cc], dv);
      }
#pragma unroll
      for (int off = 1; off < 16; off <<= 1) {
        sv += __shfl_xor(sv, off);
        dv += __shfl_xor(dv, off);
      }
      if ((lane & 15) == 0) {
        int n = n0 + q * 8 + rr;
        src[(size_t)(b * 4 + hh) * 2048 + n] = sv;
        dst[(size_t)(b * 4 + hh) * 2048 + n] = dv;
        dmx = fmaxf(dmx, dv);
      }
    }
    if ((lane & 15) == 0) atomicMax(&dmaxU[b * 4 + hh], encf(dmx));
  }

  // ---- transpose through LDS (pad 33 -> conflict-free), emit bf16 wht
#pragma unroll
  for (int rr = 0; rr < 8; rr++)
#pragma unroll
    for (int cc = 0; cc < 4; cc++)
      tr[(lane * 4 + cc) * 33 + q * 8 + rr] = acc[rr][cc];
  __syncthreads();

  int c = t;                 // output channel 0..255
  int d = c & 63, hh = c >> 6;
  u32x4 wv[4];
#pragma unroll
  for (int i = 0; i < 4; i++) {
#pragma unroll
    for (int jj = 0; jj < 4; jj++) {
      unsigned lo = f2bf(tr[c * 33 + (i * 4 + jj) * 2]);
      unsigned hi = f2bf(tr[c * 33 + (i * 4 + jj) * 2 + 1]);
      wv[i][jj] = lo | (hi << 16);
    }
  }
  u32x4* outp = (u32x4*)(wht + ((size_t)((b * H_ + hh) * 64 + d)) * 2048 + n0);
#pragma unroll
  for (int i = 0; i < 4; i++) outp[i] = wv[i];
}

// ---------------- Kernel C: flash attention, j split across wave-halves ---
// 512 threads: waves 0-3 handle j in [0,1024), waves 4-7 j in [1024,2048),
// each half with its own double-buffered Wh tile pipeline. Numerator and
// denominator combined through LDS at the end (no global partials).
__global__ __launch_bounds__(512) void k_attn(const unsigned* __restrict__ adjb,
                                              const unsigned short* __restrict__ wht,
                                              const float* __restrict__ src,
                                              const float* __restrict__ dst,
                                              const unsigned* __restrict__ dmaxU,
                                              float* __restrict__ hnew,
                                              float* __restrict__ chsum,
                                              float* __restrict__ chsq) {
  __shared__ unsigned adj_lds[64 * 65];   // 16.6KB; reused as f32 acc-combine buf
  __shared__ u32x4 whb4[2048];            // 2 halves x 2 dbuf x 8KB, XOR-swizzled
  __shared__ f32x4 dstl4[512];            // full dstL row for this bh (8KB)
  __shared__ float redS[256], redQ[256], ddl[64];

  int t = threadIdx.x;
  int bid = blockIdx.x;
  int bh = bid & 15, it = bid >> 4;       // 16 consecutive blocks share adj rows (L2)
  int b = bh >> 2, hh = bh & 3;
  int i0 = it * 64;
  int w8 = t >> 6, half = w8 >> 2, w = w8 & 3;
  int lane = t & 63, m = lane & 15, g = lane >> 4;

  for (int idx = t; idx < 64 * 64; idx += 512) {
    int r = idx >> 6, wd = idx & 63;
    adj_lds[r * 65 + wd] = adjb[(size_t)(i0 + r) * 64 + wd];
  }
  dstl4[t] = ((const f32x4*)(dst + (size_t)bh * 2048))[t];
  const float* dstl = (const float*)dstl4;

  int row_i = i0 + w * 16 + m;            // A-operand row this lane fills
  float srcL = src[(size_t)bh * 2048 + row_i];
  float dmaxL = decf(dmaxU[bh]);
  float sML = srcL + dmaxL;
  float negM = -fmaxf(sML, LEAKY * sML);  // -(row score upper bound), log2 domain

  f32x4 acc[4];
#pragma unroll
  for (int db = 0; db < 4; db++) acc[db] = (f32x4){0.f, 0.f, 0.f, 0.f};
  float den = 0.f;

  char* wbase = (char*)whb4 + half * 16384;
  int ts = t & 255;
  int r_ = ts >> 2, ch_ = ts & 3;
  int jtbase = half * 16;
  const char* gbase = (const char*)(wht + (size_t)(bh * 64 + r_) * 2048) + jtbase * 128;
  int sw = (r_ & 7) << 4;
  u32x4 R0, R1;

#define LOADT(jt_) { const u32x4* gp = (const u32x4*)(gbase + (jt_) * 128 + ch_ * 32); \
                     R0 = gp[0]; R1 = gp[1]; }
#define WRITET(pb_) { char* wb_ = (pb_); \
                      *(u32x4*)(wb_ + r_ * 128 + ((ch_ * 32) ^ sw)) = R0; \
                      *(u32x4*)(wb_ + r_ * 128 + ((ch_ * 32 + 16) ^ sw)) = R1; }

  LOADT(0); WRITET(wbase); LOADT(1);

  for (int jt = 0; jt < 16; jt++) {
    int cur = jt & 1;
    __syncthreads();                      // drains prefetch vmem + dbuf writes
    if (jt < 15) WRITET(wbase + (cur ^ 1) * 8192);   // tile jt+1 -> other buf
    if (jt < 14) LOADT(jt + 2);                      // issue tile jt+2 loads
    const char* wbufc = wbase + cur * 8192;
    int jglob = jtbase + jt;

#pragma unroll
    for (int ks = 0; ks < 2; ks++) {
      unsigned adjw = adj_lds[(w * 16 + m) * 65 + jglob * 2 + ks];
      unsigned bits = (adjw >> (g * 8)) & 0xffu;
      const float* dp = &dstl[jglob * 64 + ks * 32 + g * 8];
      f32x4 dv0 = *(const f32x4*)dp;
      f32x4 dv1 = *(const f32x4*)(dp + 4);
      float pm[8];
#pragma unroll
      for (int e = 0; e < 8; e++) {
        float dj = (e < 4) ? dv0[e] : dv1[e - 4];
        float svL = srcL + dj;
        float ex = fmaxf(svL + negM, fmaf(LEAKY, svL, negM));  // leaky, log2 dom
        float p = __builtin_amdgcn_exp2f(ex);
        unsigned keep = (unsigned)(((int)(bits << (31 - e))) >> 31);
        p = __builtin_bit_cast(float, __builtin_bit_cast(unsigned, p) & keep);
        den += p;
        pm[e] = p;
      }
      u32x4 afu;
#pragma unroll
      for (int e2 = 0; e2 < 4; e2++) {
        unsigned rr_;
        asm("v_cvt_pk_bf16_f32 %0, %1, %2" : "=v"(rr_) : "v"(pm[2 * e2]), "v"(pm[2 * e2 + 1]));
        afu[e2] = rr_;
      }
      s16x8 af = __builtin_bit_cast(s16x8, afu);
#pragma unroll
      for (int db = 0; db < 4; db++) {
        int dl = db * 16 + m;
        int off = dl * 128 + ((ks * 64 + g * 16) ^ ((dl & 7) << 4));
        s16x8 bf = *(const s16x8*)(wbufc + off);
        acc[db] = __builtin_amdgcn_mfma_f32_16x16x32_bf16(af, bf, acc[db], 0, 0, 0);
      }
    }
  }
#undef LOADT
#undef WRITET

  // per-row half-denominator (sum across the 4 k-groups of this wave)
  den += __shfl_xor(den, 16);
  den += __shfl_xor(den, 32);

  __syncthreads();                        // both halves done with adj_lds reads
  float* accl = (float*)adj_lds;          // reuse as [row][d] stride-65 buffer
  if (half == 1) {
    if (lane < 16) ddl[w * 16 + lane] = den;
#pragma unroll
    for (int db = 0; db < 4; db++)
#pragma unroll
      for (int r = 0; r < 4; r++)
        accl[(w * 16 + 4 * g + r) * 65 + db * 16 + m] = acc[db][r];
  }
  __syncthreads();

  if (half == 0) {
    float dtot = den + ddl[w * 16 + m];
#pragma unroll
    for (int db = 0; db < 4; db++)
#pragma unroll
      for (int r = 0; r < 4; r++)
        acc[db][r] += accl[(w * 16 + 4 * g + r) * 65 + db * 16 + m];

    float sums[4] = {0.f, 0.f, 0.f, 0.f}, sqs[4] = {0.f, 0.f, 0.f, 0.f};
#pragma unroll
    for (int r = 0; r < 4; r++) {
      float dr = __shfl(dtot, 4 * g + r);     // denominator for D-layout row 4g+r
      float inv = dr > 0.f ? 1.0f / dr : 0.f; // all-masked row -> zeros (nan_to_num)
      int n = i0 + w * 16 + 4 * g + r;
#pragma unroll
      for (int db = 0; db < 4; db++) {
        float val = acc[db][r] * inv;
        hnew[(size_t)(b * 2048 + n) * 256 + hh * 64 + db * 16 + m] = val;
        sums[db] += val;
        sqs[db] += val * val;
      }
    }
#pragma unroll
    for (int db = 0; db < 4; db++) {
      sums[db] += __shfl_xor(sums[db], 16); sums[db] += __shfl_xor(sums[db], 32);
      sqs[db]  += __shfl_xor(sqs[db], 16);  sqs[db]  += __shfl_xor(sqs[db], 32);
    }
    if (g == 0) {
#pragma unroll
      for (int db = 0; db < 4; db++) {
        redS[w * 64 + db * 16 + m] = sums[db];
        redQ[w * 64 + db * 16 + m] = sqs[db];
      }
    }
  }
  __syncthreads();
  if (t < 64) {
    float ts2 = redS[t] + redS[64 + t] + redS[128 + t] + redS[192 + t];
    float tq = redQ[t] + redQ[64 + t] + redQ[128 + t] + redQ[192 + t];
    atomicAdd(&chsum[hh * 64 + t], ts2);
    atomicAdd(&chsq[hh * 64 + t], tq);
  }
}

// ---------------- Kernel D: BN stats -> scale/shift -----------------------
__global__ void k_stats(const float* __restrict__ chsum, const float* __restrict__ chsq,
                        const float* __restrict__ gamma, const float* __restrict__ beta,
                        float* __restrict__ scale, float* __restrict__ shift) {
  int c = threadIdx.x;
  float mean = chsum[c] * (1.0f / 8192.0f);
  float var = chsq[c] * (1.0f / 8192.0f) - mean * mean;
  float sc = gamma[c] * rsqrtf(var + BNEPS);
  scale[c] = sc;
  shift[c] = beta[c] - mean * sc;
}

// ---------------- Kernel E: BN apply + ELU --------------------------------
__global__ __launch_bounds__(256) void k_bn_elu(const float* __restrict__ hnew,
                                                const float* __restrict__ scale,
                                                const float* __restrict__ shift,
                                                float* __restrict__ out) {
  int idx4 = blockIdx.x * 256 + threadIdx.x;
  f32x4 x = ((const f32x4*)hnew)[idx4];
  int c0 = (idx4 * 4) & 255;
  f32x4 sc = *(const f32x4*)(scale + c0);
  f32x4 sh = *(const f32x4*)(shift + c0);
  f32x4 y;
#pragma unroll
  for (int e = 0; e < 4; e++) {
    float v = fmaf(x[e], sc[e], sh[e]);
    y[e] = v > 0.f ? v : expm1f(v);
  }
  ((f32x4*)out)[idx4] = y;
}

extern "C" void kernel_launch(void* const* d_in, const int* in_sizes, int n_in,
                              void* d_out, int out_size, void* d_ws, size_t ws_size,
                              hipStream_t stream) {
  const float* h = (const float*)d_in[0];
  const float* W = (const float*)d_in[1];
  const float* a = (const float*)d_in[2];
  const float* gamma = (const float*)d_in[3];
  const float* beta = (const float*)d_in[4];
  const int* adj = (const int*)d_in[5];

  char* ws = (char*)d_ws;
  unsigned* adjb = (unsigned*)ws;                                  // 512 KB
  unsigned short* wht = (unsigned short*)(ws + (512 << 10));       // 4 MB
  float* src = (float*)(ws + (512 << 10) + (4 << 20));             // 128 KB
  float* dst = src + 16 * 2048;                                    // 128 KB
  float* chsum = dst + 16 * 2048;                                  // 256
  float* chsq = chsum + 256;                                       // 256
  unsigned* dmaxU = (unsigned*)(chsq + 256);                       // 64
  float* scale = (float*)(dmaxU + 64);                             // 256
  float* shift = scale + 256;                                      // 256
  float* hnew = (float*)(ws + (512 << 10) + (5 << 20));            // 8 MB

  k_pack_adj<<<(N_ * N_) / 256, 256, 0, stream>>>(adj, adjb, chsum);
  k_gemm<<<(B_ * N_) / 32, 256, 0, stream>>>(h, W, a, wht, src, dst, dmaxU);
  k_attn<<<B_ * H_ * (N_ / 64), 512, 0, stream>>>(adjb, wht, src, dst, dmaxU,
                                                  hnew, chsum, chsq);
  k_stats<<<1, 256, 0, stream>>>(chsum, chsq, gamma, beta, scale, shift);
  k_bn_elu<<<(B_ * N_ * HD_) / 1024, 256, 0, stream>>>(hnew, scale, shift,
                                                       (float*)d_out);
}